// Round 12
// baseline (320.480 us; speedup 1.0000x reference)
//
#include <hip/hip_runtime.h>
#include <stdint.h>

// Round 22: combine r21's qkv (bn-ownership XCD map, verified) with r20's
// ffn2 (128x64 depth-2 counted-vmcnt pipeline, verified). r20's ffn2 time
// was never observed (top-5 was all regressed-qkv rows); ledger arithmetic
// says it was likely ~45us (staged 804MB / 20TB/s), and r21's revert cost
// us that win. This round disambiguates with both best pieces in place.
// Everything else frozen at r21 (total 317.6). ws: 127 MB.

using short8 = __attribute__((ext_vector_type(8))) short;
using f32x4  = __attribute__((ext_vector_type(4))) float;

__device__ __forceinline__ uint16_t f2bf(float f) {
  uint32_t u = __builtin_bit_cast(uint32_t, f);
  u += 0x7FFFu + ((u >> 16) & 1u);        // RNE, inputs are finite
  return (uint16_t)(u >> 16);
}

__device__ __forceinline__ float bf2f(uint16_t u) {
  return __builtin_bit_cast(float, (uint32_t)u << 16);
}

__device__ __forceinline__ void gload_lds16(const uint16_t* g, uint16_t* l) {
  __builtin_amdgcn_global_load_lds(
      (__attribute__((address_space(1))) void*)(void*)g,
      (__attribute__((address_space(3))) void*)l, 16, 0, 0);
}

// LDS swizzle (BK=64): 16B slot s holds global chunk-col (s&7)^((s>>3)&7) of
// row s>>3. Read (row r, chunk cc) -> slot r*8 + (cc ^ (r&7)).

// ------------- QKV gemm: 128x128, bn-ownership XCD map, grid 768 ------------
// x=id&7, t=id>>3: bn = x*3 + t%3 (each XCD owns 3 WqkvT stripes, 768KB
// L2-resident), bm = t/3 (A streams once per XCD). Bijective 8x3x32.
__global__ __launch_bounds__(256) void gemm_qkv(
    const uint16_t* __restrict__ A, const uint16_t* __restrict__ Bt,
    const float* __restrict__ bias, uint16_t* __restrict__ Cout,
    uint16_t* __restrict__ Vt)
{
  constexpr int BK = 64;
  __shared__ uint16_t As[128 * BK];
  __shared__ uint16_t Bs[128 * BK];
  int id = blockIdx.x;
  int x = id & 7, t = id >> 3;
  int bn = x * 3 + t % 3;
  int bm = t / 3;
  bool vblk = (bn >= 16);

  int tid  = threadIdx.x;
  int lane = tid & 63;
  int wave = tid >> 6;
  int wm = (wave >> 1) * 64, wn = (wave & 1) * 64;
  int lr = lane & 15, quad = lane >> 4;

  const uint16_t *Ag[4], *Bg[4];
  uint16_t *Al[4], *Bl[4];
#pragma unroll
  for (int s = 0; s < 4; ++s) {
    int c = tid + 256 * s;
    int r = c >> 3, q = (c & 7) ^ (r & 7);
    Ag[s] = A  + (size_t)(bm * 128 + r) * 1024 + q * 8;
    Bg[s] = Bt + (size_t)(bn * 128 + r) * 1024 + q * 8;
    Al[s] = As + c * 8;
    Bl[s] = Bs + c * 8;
  }
  const uint16_t* Fa = vblk ? Bs : As;
  const uint16_t* Fb = vblk ? As : Bs;

  f32x4 acc[4][4] = {};

  for (int k0 = 0; k0 < 1024; k0 += BK) {
    __syncthreads();
#pragma unroll
    for (int s = 0; s < 4; ++s) gload_lds16(Ag[s] + k0, Al[s]);
#pragma unroll
    for (int s = 0; s < 4; ++s) gload_lds16(Bg[s] + k0, Bl[s]);
    __syncthreads();
#pragma unroll
    for (int h = 0; h < 2; ++h) {
      short8 af[4], bfr[4];
      int cc = quad + 4 * h;
#pragma unroll
      for (int i = 0; i < 4; ++i) {
        int r = wm + i * 16 + lr;
        af[i] = *(const short8*)(&Fa[(r * 8 + (cc ^ (r & 7))) * 8]);
      }
#pragma unroll
      for (int j = 0; j < 4; ++j) {
        int r = wn + j * 16 + lr;
        bfr[j] = *(const short8*)(&Fb[(r * 8 + (cc ^ (r & 7))) * 8]);
      }
#pragma unroll
      for (int i = 0; i < 4; ++i)
#pragma unroll
        for (int j = 0; j < 4; ++j)
          acc[i][j] = __builtin_amdgcn_mfma_f32_16x16x32_bf16(af[i], bfr[j], acc[i][j], 0, 0, 0);
    }
  }

  if (vblk) {
#pragma unroll
    for (int i = 0; i < 4; ++i) {
#pragma unroll
      for (int r = 0; r < 4; ++r) {
        int n = bn * 128 + wm + i * 16 + quad * 4 + r;
        float bv = bias[n];
        uint16_t* dst = Vt + (size_t)(n - 2048) * 4096 + bm * 128;
#pragma unroll
        for (int j = 0; j < 4; ++j)
          dst[wn + j * 16 + lr] = f2bf(acc[i][j][r] + bv);
      }
    }
  } else {
    int row0 = bm * 128 + wm + quad * 4;
    int col0 = bn * 128 + wn + lr;
#pragma unroll
    for (int j = 0; j < 4; ++j) {
      int col = col0 + j * 16;
      float bv = bias[col];
#pragma unroll
      for (int i = 0; i < 4; ++i)
#pragma unroll
        for (int r = 0; r < 4; ++r)
          Cout[(size_t)(row0 + i * 16 + r) * 3072 + col] = f2bf(acc[i][j][r] + bv);
    }
  }
}

// ---------------- FFN1 gemm: 128x128, bn-quad XCD ownership, grid 1024 ------
// x=id&7, bn = x*4 + ((id>>3)&3), bm = id>>5 (bijective 8x4x32). Each XCD
// permanently owns 4 bn-stripes (1MB W1T L2-resident); A-stripes are shared
// by the 4 resident bn-blocks and stream through once per XCD.
__global__ __launch_bounds__(256) void gemm_ffn1(
    const uint16_t* __restrict__ A, const uint16_t* __restrict__ Bt,
    const float* __restrict__ bias, uint16_t* __restrict__ Cout)
{
  constexpr int BK = 64;
  __shared__ uint16_t As[128 * BK];
  __shared__ uint16_t Bs[128 * BK];
  int id = blockIdx.x;
  int bn = (id & 7) * 4 + ((id >> 3) & 3);
  int bm = id >> 5;

  int tid  = threadIdx.x;
  int lane = tid & 63;
  int wave = tid >> 6;
  int wm = (wave >> 1) * 64, wn = (wave & 1) * 64;
  int lr = lane & 15, quad = lane >> 4;

  const uint16_t *Ag[4], *Bg[4];
  uint16_t *Al[4], *Bl[4];
#pragma unroll
  for (int s = 0; s < 4; ++s) {
    int c = tid + 256 * s;
    int r = c >> 3, q = (c & 7) ^ (r & 7);
    Ag[s] = A  + (size_t)(bm * 128 + r) * 1024 + q * 8;
    Bg[s] = Bt + (size_t)(bn * 128 + r) * 1024 + q * 8;
    Al[s] = As + c * 8;
    Bl[s] = Bs + c * 8;
  }

  f32x4 acc[4][4] = {};

  for (int k0 = 0; k0 < 1024; k0 += BK) {
    __syncthreads();
#pragma unroll
    for (int s = 0; s < 4; ++s) gload_lds16(Ag[s] + k0, Al[s]);
#pragma unroll
    for (int s = 0; s < 4; ++s) gload_lds16(Bg[s] + k0, Bl[s]);
    __syncthreads();
#pragma unroll
    for (int h = 0; h < 2; ++h) {
      short8 af[4], bfr[4];
      int cc = quad + 4 * h;
#pragma unroll
      for (int i = 0; i < 4; ++i) {
        int r = wm + i * 16 + lr;
        af[i] = *(const short8*)(&As[(r * 8 + (cc ^ (r & 7))) * 8]);
      }
#pragma unroll
      for (int j = 0; j < 4; ++j) {
        int r = wn + j * 16 + lr;
        bfr[j] = *(const short8*)(&Bs[(r * 8 + (cc ^ (r & 7))) * 8]);
      }
#pragma unroll
      for (int i = 0; i < 4; ++i)
#pragma unroll
        for (int j = 0; j < 4; ++j)
          acc[i][j] = __builtin_amdgcn_mfma_f32_16x16x32_bf16(af[i], bfr[j], acc[i][j], 0, 0, 0);
    }
  }

  int row0 = bm * 128 + wm + quad * 4;
  int col0 = bn * 128 + wn + lr;
#pragma unroll
  for (int j = 0; j < 4; ++j) {
    int col = col0 + j * 16;
    float bv = bias[col];
#pragma unroll
    for (int i = 0; i < 4; ++i)
#pragma unroll
      for (int r = 0; r < 4; ++r)
        Cout[(size_t)(row0 + i * 16 + r) * 4096 + col] =
            f2bf(fmaxf(acc[i][j][r] + bv, 0.0f));
  }
}

// ---------------- causal S-gemm, 64x128 tiles, XCD-swizzled -----------------
// 1-D grid 2048: i64 = id&63 (Q-tile sharers co-XCD), bn = id>>6;
// early-exit if bn > i64>>1. Fused row-sum atomics into lvec.
__global__ __launch_bounds__(256) void gemm_s(
    const uint16_t* __restrict__ Qm, const uint16_t* __restrict__ Km,
    uint16_t* __restrict__ Sb, float* __restrict__ lvec,
    int lda, int ldb, int ldc, float scale)
{
  constexpr int BK = 64;
  __shared__ uint16_t As[64 * BK];
  __shared__ uint16_t Bs[128 * BK];
  int id = blockIdx.x;
  int i64 = id & 63, bn = id >> 6;
  if (bn > (i64 >> 1)) return;

  int tid  = threadIdx.x;
  int lane = tid & 63;
  int wave = tid >> 6;
  int wm = (wave >> 1) * 32, wn = (wave & 1) * 64;
  int lr = lane & 15, quad = lane >> 4;

  const uint16_t *Ag[2], *Bg[4];
  uint16_t *Al[2], *Bl[4];
#pragma unroll
  for (int s = 0; s < 2; ++s) {
    int c = tid + 256 * s;
    int r = c >> 3, q = (c & 7) ^ (r & 7);
    Ag[s] = Qm + (size_t)(i64 * 64 + r) * lda + q * 8;
    Al[s] = As + c * 8;
  }
#pragma unroll
  for (int s = 0; s < 4; ++s) {
    int c = tid + 256 * s;
    int r = c >> 3, q = (c & 7) ^ (r & 7);
    Bg[s] = Km + (size_t)(bn * 128 + r) * ldb + q * 8;
    Bl[s] = Bs + c * 8;
  }

  f32x4 acc[2][4] = {};

  for (int k0 = 0; k0 < 1024; k0 += BK) {
    __syncthreads();
#pragma unroll
    for (int s = 0; s < 2; ++s) gload_lds16(Ag[s] + k0, Al[s]);
#pragma unroll
    for (int s = 0; s < 4; ++s) gload_lds16(Bg[s] + k0, Bl[s]);
    __syncthreads();
#pragma unroll
    for (int h = 0; h < 2; ++h) {
      short8 af[2], bfr[4];
      int cc = quad + 4 * h;
#pragma unroll
      for (int i = 0; i < 2; ++i) {
        int r = wm + i * 16 + lr;
        af[i] = *(const short8*)(&As[(r * 8 + (cc ^ (r & 7))) * 8]);
      }
#pragma unroll
      for (int j = 0; j < 4; ++j) {
        int r = wn + j * 16 + lr;
        bfr[j] = *(const short8*)(&Bs[(r * 8 + (cc ^ (r & 7))) * 8]);
      }
#pragma unroll
      for (int i = 0; i < 2; ++i)
#pragma unroll
        for (int j = 0; j < 4; ++j)
          acc[i][j] = __builtin_amdgcn_mfma_f32_16x16x32_bf16(af[i], bfr[j], acc[i][j], 0, 0, 0);
    }
  }

  int row0 = i64 * 64 + wm + quad * 4;
  int col0 = bn * 128 + wn + lr;
#pragma unroll
  for (int i = 0; i < 2; ++i) {
#pragma unroll
    for (int r = 0; r < 4; ++r) {
      int row = row0 + i * 16 + r;
      float s = 0.0f;
#pragma unroll
      for (int j = 0; j < 4; ++j) {
        int col = col0 + j * 16;
        float v = (col <= row) ? __expf(acc[i][j][r] * scale) : 0.0f;
        Sb[(size_t)row * ldc + col] = f2bf(v);
        s += v;
      }
#pragma unroll
      for (int o = 8; o > 0; o >>= 1) s += __shfl_xor(s, o, 64);
      if (lr == 0) unsafeAtomicAdd(&lvec[row], s);
    }
  }
}

// ---------------- O-gemm: 128x128, triangular K-chunks, XCD-swizzled --------
// 1-D grid 640: id = bn*80 + p (id%8==p%8 co-XCD). p ordered LONG-FIRST.
// Opart partials bf16 (r18: verified absmax unchanged).
__global__ __launch_bounds__(256) void gemm_o(
    const uint16_t* __restrict__ Sb, const uint16_t* __restrict__ Vt,
    uint16_t* __restrict__ Opart)
{
  constexpr int BK = 64;
  __shared__ uint16_t As[128 * BK];
  __shared__ uint16_t Bs[128 * BK];
  int id = blockIdx.x;
  int bn = id / 80, p = id % 80;
  int c, bm;
  if      (p < 25) { c = 0; bm = 7 + p; }
  else if (p < 49) { c = 1; bm = 8 + (p - 25); }
  else if (p < 65) { c = 2; bm = 16 + (p - 49); }
  else if (p < 73) { c = 3; bm = 24 + (p - 65); }
  else             { c = 0; bm = 79 - p; }
  int klo = c << 10;
  int khi = (bm + 1) << 7; if (khi > ((c + 1) << 10)) khi = (c + 1) << 10;

  int tid  = threadIdx.x;
  int lane = tid & 63;
  int wave = tid >> 6;
  int wm = (wave >> 1) * 64, wn = (wave & 1) * 64;
  int lr = lane & 15, quad = lane >> 4;

  const uint16_t *Ag[4], *Bg[4];
  uint16_t *Al[4], *Bl[4];
#pragma unroll
  for (int s = 0; s < 4; ++s) {
    int cch = tid + 256 * s;
    int r = cch >> 3, q = (cch & 7) ^ (r & 7);
    Ag[s] = Sb + (size_t)(bm * 128 + r) * 4096 + q * 8;
    Bg[s] = Vt + (size_t)(bn * 128 + r) * 4096 + q * 8;
    Al[s] = As + cch * 8;
    Bl[s] = Bs + cch * 8;
  }

  f32x4 acc[4][4] = {};

  for (int k0 = klo; k0 < khi; k0 += BK) {
    __syncthreads();
#pragma unroll
    for (int s = 0; s < 4; ++s) gload_lds16(Ag[s] + k0, Al[s]);
#pragma unroll
    for (int s = 0; s < 4; ++s) gload_lds16(Bg[s] + k0, Bl[s]);
    __syncthreads();
#pragma unroll
    for (int h = 0; h < 2; ++h) {
      short8 af[4], bfr[4];
      int cc = quad + 4 * h;
#pragma unroll
      for (int i = 0; i < 4; ++i) {
        int r = wm + i * 16 + lr;
        af[i] = *(const short8*)(&As[(r * 8 + (cc ^ (r & 7))) * 8]);
      }
#pragma unroll
      for (int j = 0; j < 4; ++j) {
        int r = wn + j * 16 + lr;
        bfr[j] = *(const short8*)(&Bs[(r * 8 + (cc ^ (r & 7))) * 8]);
      }
#pragma unroll
      for (int i = 0; i < 4; ++i)
#pragma unroll
        for (int j = 0; j < 4; ++j)
          acc[i][j] = __builtin_amdgcn_mfma_f32_16x16x32_bf16(af[i], bfr[j], acc[i][j], 0, 0, 0);
    }
  }

  uint16_t* P = Opart + (size_t)c * 4194304;
  int row0 = bm * 128 + wm + quad * 4;
  int col0 = bn * 128 + wn + lr;
#pragma unroll
  for (int j = 0; j < 4; ++j)
#pragma unroll
    for (int i = 0; i < 4; ++i)
#pragma unroll
      for (int r = 0; r < 4; ++r)
        P[(size_t)(row0 + i * 16 + r) * 1024 + col0 + j * 16] = f2bf(acc[i][j][r]);
}

// ---------------- FFN2: 128x64, counted-vmcnt depth-2, r13-style map --------
// grid 512: bn = id>>5, bm = id&31 (A-stripe sharers co-XCD via id%8==bm%8).
// K=4096 unsplit. STAGE = 6 loads (4 A + 2 B); depth-2 -> 12 outstanding,
// s_waitcnt vmcnt(6) steady-state, tail 6 -> 0. LDS 2x24KB = 48KB.
// (Ran + passed in r20; its dur was never observed — this round observes it.)
__global__ __launch_bounds__(256) void gemm_ffn2(
    const uint16_t* __restrict__ A, const uint16_t* __restrict__ Bt,
    const float* __restrict__ bias, float* __restrict__ Cout)
{
  constexpr int BK = 64;
  __shared__ uint16_t AsB[2][128 * BK];
  __shared__ uint16_t BsB[2][64 * BK];
  int id = blockIdx.x;
  int bn = id >> 5, bm = id & 31;

  int tid  = threadIdx.x;
  int lane = tid & 63;
  int wave = tid >> 6;
  int wm = (wave >> 1) * 64, wn = (wave & 1) * 32;
  int lr = lane & 15, quad = lane >> 4;

  const uint16_t *Ag[4], *Bg[2];
  int offA[4], offB[2];
#pragma unroll
  for (int s = 0; s < 4; ++s) {
    int c = tid + 256 * s;
    int r = c >> 3, q = (c & 7) ^ (r & 7);
    Ag[s] = A + (size_t)(bm * 128 + r) * 4096 + q * 8;
    offA[s] = c * 8;
  }
#pragma unroll
  for (int s = 0; s < 2; ++s) {
    int c = tid + 256 * s;
    int r = c >> 3, q = (c & 7) ^ (r & 7);
    Bg[s] = Bt + (size_t)(bn * 64 + r) * 4096 + q * 8;
    offB[s] = c * 8;
  }

  f32x4 acc[4][2] = {};

  // 6 loads per thread per STAGE, FIFO order A0..A3,B0,B1.
  auto STAGE = [&](uint16_t* Ab, uint16_t* Bb, int k0) {
#pragma unroll
    for (int s = 0; s < 4; ++s) gload_lds16(Ag[s] + k0, Ab + offA[s]);
#pragma unroll
    for (int s = 0; s < 2; ++s) gload_lds16(Bg[s] + k0, Bb + offB[s]);
  };
  auto COMP = [&](const uint16_t* Ab, const uint16_t* Bb) {
#pragma unroll
    for (int h = 0; h < 2; ++h) {
      short8 af[4], bfr[2];
      int cc = quad + 4 * h;
#pragma unroll
      for (int i = 0; i < 4; ++i) {
        int r = wm + i * 16 + lr;
        af[i] = *(const short8*)(&Ab[(r * 8 + (cc ^ (r & 7))) * 8]);
      }
#pragma unroll
      for (int j = 0; j < 2; ++j) {
        int r = wn + j * 16 + lr;
        bfr[j] = *(const short8*)(&Bb[(r * 8 + (cc ^ (r & 7))) * 8]);
      }
#pragma unroll
      for (int i = 0; i < 4; ++i)
#pragma unroll
        for (int j = 0; j < 2; ++j)
          acc[i][j] = __builtin_amdgcn_mfma_f32_16x16x32_bf16(af[i], bfr[j], acc[i][j], 0, 0, 0);
    }
  };

  uint16_t *cA = &AsB[0][0], *cB = &BsB[0][0];
  uint16_t *nA = &AsB[1][0], *nB = &BsB[1][0];

  STAGE(cA, cB, 0);        // step 0 (oldest 6)
  STAGE(nA, nB, BK);       // step 1 — 12 outstanding

  for (int t = 0; t < 62; ++t) {
    asm volatile("s_waitcnt vmcnt(6)" ::: "memory");  // cur buffer complete
    __builtin_amdgcn_s_barrier();                     // ...for ALL waves
    COMP(cA, cB);
    __builtin_amdgcn_s_barrier();                     // all done reading cur
    STAGE(cA, cB, (t + 2) * BK);                      // overwrite cur for t+2
    uint16_t* tp;
    tp = cA; cA = nA; nA = tp;
    tp = cB; cB = nB; nB = tp;
  }
  // step 62: outstanding = stage62(6, oldest) + stage63(6)
  asm volatile("s_waitcnt vmcnt(6)" ::: "memory");
  __builtin_amdgcn_s_barrier();
  COMP(cA, cB);
  // step 63: drain the final 6
  asm volatile("s_waitcnt vmcnt(0)" ::: "memory");
  __builtin_amdgcn_s_barrier();
  COMP(nA, nB);

  int row0 = bm * 128 + wm + quad * 4;
  int col0 = bn * 64 + wn + lr;
#pragma unroll
  for (int j = 0; j < 2; ++j) {
    int col = col0 + j * 16;
    float bv = bias[col];
#pragma unroll
    for (int i = 0; i < 4; ++i)
#pragma unroll
      for (int r = 0; r < 4; ++r)
        Cout[(size_t)(row0 + i * 16 + r) * 1024 + col] = acc[i][j][r] + bv;
  }
}

// ---------------- reductions ------------------------------------------------
__device__ __forceinline__ float block_sum(float v, float* red) {
#pragma unroll
  for (int o = 32; o > 0; o >>= 1) v += __shfl_xor(v, o, 64);
  if ((threadIdx.x & 63) == 0) red[threadIdx.x >> 6] = v;
  __syncthreads();
  v = red[0] + red[1] + red[2] + red[3];
  __syncthreads();
  return v;
}

// ------ O-chunk bf16 partials reduce /l + residual + LayerNorm -> bf16 ------
__global__ __launch_bounds__(256) void add_layernorm(
    const uint16_t* __restrict__ P, const float* __restrict__ l,
    const float* __restrict__ emb, const float* __restrict__ gamma,
    const float* __restrict__ beta, uint16_t* __restrict__ xB)
{
  __shared__ float red[4];
  int i = blockIdx.x, tid = threadIdx.x;
  float inv_l = 1.0f / l[i];
  int nc = (i >> 10) + 1;
  float s0 = 0.0f, s1 = 0.0f, s2 = 0.0f, s3 = 0.0f;
  for (int c = 0; c < nc; ++c) {
    ushort4 a = ((const ushort4*)(P + (size_t)c * 4194304 + (size_t)i * 1024))[tid];
    s0 += bf2f(a.x); s1 += bf2f(a.y); s2 += bf2f(a.z); s3 += bf2f(a.w);
  }
  float4 b = ((const float4*)(emb + (size_t)i * 1024))[tid];
  float x0 = s0 * inv_l + b.x, x1 = s1 * inv_l + b.y;
  float x2 = s2 * inv_l + b.z, x3 = s3 * inv_l + b.w;
  float mu = block_sum(x0 + x1 + x2 + x3, red) * (1.0f / 1024.0f);
  float d0 = x0 - mu, d1 = x1 - mu, d2 = x2 - mu, d3 = x3 - mu;
  float var = block_sum(d0 * d0 + d1 * d1 + d2 * d2 + d3 * d3, red) * (1.0f / 1024.0f);
  float rs = rsqrtf(var + 1e-5f);
  float4 g  = ((const float4*)gamma)[tid];
  float4 be = ((const float4*)beta)[tid];
  ushort4 o;
  o.x = f2bf(d0 * rs * g.x + be.x);
  o.y = f2bf(d1 * rs * g.y + be.y);
  o.z = f2bf(d2 * rs * g.z + be.z);
  o.w = f2bf(d3 * rs * g.w + be.w);
  ((ushort4*)(xB + (size_t)i * 1024))[tid] = o;
}

// ---------------- prep: all casts/transposes/bias/init in one launch --------
__global__ __launch_bounds__(256) void prep(
    const float* __restrict__ emb, const float* __restrict__ Wq,
    const float* __restrict__ Wk, const float* __restrict__ Wv,
    const float* __restrict__ W1, const float* __restrict__ W2,
    const float* __restrict__ bq, const float* __restrict__ bk,
    const float* __restrict__ bv, uint16_t* __restrict__ embB,
    uint16_t* __restrict__ WqkvT, uint16_t* __restrict__ W1T,
    uint16_t* __restrict__ W2T, float* __restrict__ bqkv,
    float* __restrict__ lvec)
{
  __shared__ float tile[32][33];
  int b = blockIdx.x, tid = threadIdx.x;
  if (b < 4096) {                        // emb cast
    int idx = b * 256 + tid;
    float4 v = ((const float4*)emb)[idx];
    ushort4 o; o.x = f2bf(v.x); o.y = f2bf(v.y); o.z = f2bf(v.z); o.w = f2bf(v.w);
    ((ushort4*)embB)[idx] = o;
    return;
  }
  int tx = tid & 31, ty = tid >> 5;
  if (b < 7168) {                        // Wq/Wk/Wv -> WqkvT
    int local = b - 4096;
    const float* in = (local < 1024) ? Wq : (local < 2048) ? Wk : Wv;
    uint16_t* o = WqkvT + (size_t)(local >> 10) * 1048576;
    int rem = local & 1023;
    int r0 = (rem >> 5) * 32, c0 = (rem & 31) * 32;
#pragma unroll
    for (int r = 0; r < 32; r += 8)
      tile[ty + r][tx] = in[(size_t)(r0 + ty + r) * 1024 + c0 + tx];
    __syncthreads();
#pragma unroll
    for (int r = 0; r < 32; r += 8)
      o[(size_t)(c0 + ty + r) * 1024 + r0 + tx] = f2bf(tile[tx][ty + r]);
    return;
  }
  if (b < 11264) {                       // W1 -> W1T
    int local = b - 7168;
    int c0 = (local & 127) * 32, r0 = (local >> 7) * 32;
#pragma unroll
    for (int r = 0; r < 32; r += 8)
      tile[ty + r][tx] = W1[(size_t)(r0 + ty + r) * 4096 + c0 + tx];
    __syncthreads();
#pragma unroll
    for (int r = 0; r < 32; r += 8)
      W1T[(size_t)(c0 + ty + r) * 1024 + r0 + tx] = f2bf(tile[tx][ty + r]);
    return;
  }
  if (b < 15360) {                       // W2 -> W2T
    int local = b - 11264;
    int c0 = (local & 31) * 32, r0 = (local >> 5) * 32;
#pragma unroll
    for (int r = 0; r < 32; r += 8)
      tile[ty + r][tx] = W2[(size_t)(r0 + ty + r) * 1024 + c0 + tx];
    __syncthreads();
#pragma unroll
    for (int r = 0; r < 32; r += 8)
      W2T[(size_t)(c0 + ty + r) * 4096 + r0 + tx] = f2bf(tile[tx][ty + r]);
    return;
  }
  if (b < 15372) {                       // pack bq|bk|bv
    int i = (b - 15360) * 256 + tid;
    bqkv[i] = (i < 1024) ? bq[i] : (i < 2048) ? bk[i - 1024] : bv[i - 2048];
    return;
  }
  {                                      // lvec = 0
#pragma unroll
    for (int i = tid; i < 4096; i += 256) lvec[i] = 0.0f;
  }
}

// ---------------- launcher --------------------------------------------------
extern "C" void kernel_launch(void* const* d_in, const int* in_sizes, int n_in,
                              void* d_out, int out_size, void* d_ws, size_t ws_size,
                              hipStream_t stream) {
  const float* emb   = (const float*)d_in[0];
  const float* Wq    = (const float*)d_in[1];
  const float* bq    = (const float*)d_in[2];
  const float* Wk    = (const float*)d_in[3];
  const float* bk    = (const float*)d_in[4];
  const float* Wv    = (const float*)d_in[5];
  const float* bv    = (const float*)d_in[6];
  const float* gamma = (const float*)d_in[7];
  const float* beta  = (const float*)d_in[8];
  const float* W1    = (const float*)d_in[9];
  const float* b1    = (const float*)d_in[10];
  const float* W2    = (const float*)d_in[11];
  const float* b2    = (const float*)d_in[12];

  char* w = (char*)d_ws;
  const size_t MB = 1ull << 20;
  uint16_t* embB  = (uint16_t*)(w + 0 * MB);    // [4096,1024] bf16
  uint16_t* WqkvT = (uint16_t*)(w + 8 * MB);    // [3072,1024]
  uint16_t* W1T   = (uint16_t*)(w + 14 * MB);   // [4096,1024]
  uint16_t* W2T   = (uint16_t*)(w + 22 * MB);   // [1024,4096]
  float*    bqkv  = (float*)(w + 30 * MB);      // [3072]
  float*    lvec  = (float*)(w + 30 * MB + 65536); // [4096]
  uint16_t* QKVb  = (uint16_t*)(w + 31 * MB);   // [4096,3072] (V cols unused)
  uint16_t* Vt    = (uint16_t*)(w + 55 * MB);   // [1024,4096]
  uint16_t* Sb    = (uint16_t*)(w + 63 * MB);   // [4096,4096] bf16 exp(S)
  uint16_t* hB    = (uint16_t*)(w + 63 * MB);   // reuses Sb (dead after O)
  uint16_t* Opart = (uint16_t*)(w + 95 * MB);   // [4][4096,1024] bf16 chunks
  uint16_t* xB    = (uint16_t*)(w + 0 * MB);    // reuses embB
  // total ws requirement: 127 MB

  prep<<<15373, 256, 0, stream>>>(emb, Wq, Wk, Wv, W1, W2, bq, bk, bv,
                                  embB, WqkvT, W1T, W2T, bqkv, lvec);

  // fused QKV: Q,K -> QKVb; V -> Vt via operand-swapped MFMA; bn-owned XCDs
  gemm_qkv<<<768, 256, 0, stream>>>(embB, WqkvT, bqkv, QKVb, Vt);
  const uint16_t* Qb = QKVb;
  const uint16_t* Kb = QKVb + 1024;

  // exp(S): 64x128 causal tiles, XCD-swizzled 2048-slot launch
  gemm_s<<<2048, 256, 0, stream>>>(Qb, Kb, Sb, lvec, 3072, 3072, 4096, 0.03125f);

  // O' = exp(S) @ V: 128x128 triangular K-chunks, XCD-swizzled, long-first
  gemm_o<<<640, 256, 0, stream>>>(Sb, Vt, Opart);

  // reduce O bf16 chunk-partials, /l, + residual, LayerNorm -> xB
  add_layernorm<<<4096, 256, 0, stream>>>(Opart, lvec, emb, gamma, beta, xB);

  // FFN1: bn-quad XCD ownership (1MB W1T L2-resident per XCD)
  gemm_ffn1<<<1024, 256, 0, stream>>>(xB, W1T, b1, hB);

  // FFN2: 128x64 counted-vmcnt depth-2 pipeline (staged 804MB vs 1.07GB)
  gemm_ffn2<<<512, 256, 0, stream>>>(hB, W2T, b2, (float*)d_out);
}

// Round 13
// 308.293 us; speedup vs baseline: 1.0395x; 1.0395x over previous
//
#include <hip/hip_runtime.h>
#include <stdint.h>

// Round 23: ffn2 -> dual-K-group block (split-K INSIDE the block).
// Model (r19-r22): staging rate scales with waves/CU (16 waves -> 20.3 TB/s,
// 8 waves -> 16.2); 128x64 tile has the low staged-bytes (804MB) but grid
// 512 = only 8 waves/CU. Fix: 512-thread blocks, 8 waves, grid 512 = 16
// waves/CU. Waves 0-3 accumulate K[0,2048), waves 4-7 K[2048,4096), each
// group with own 24KB LDS tiles, lockstep __syncthreads (32 identical
// iters/group, r18-proven drain form). Combine: group1 -> LDS f32 (stride
// 65, conflict-free, reuses dead staging LDS), barrier, group0 adds +
// writes with bias. No atomics, no extra traffic. 804MB @ ~20TB/s -> ~42us.
// Everything else frozen at r22. ws: 127 MB.

using short8 = __attribute__((ext_vector_type(8))) short;
using f32x4  = __attribute__((ext_vector_type(4))) float;

__device__ __forceinline__ uint16_t f2bf(float f) {
  uint32_t u = __builtin_bit_cast(uint32_t, f);
  u += 0x7FFFu + ((u >> 16) & 1u);        // RNE, inputs are finite
  return (uint16_t)(u >> 16);
}

__device__ __forceinline__ float bf2f(uint16_t u) {
  return __builtin_bit_cast(float, (uint32_t)u << 16);
}

__device__ __forceinline__ void gload_lds16(const uint16_t* g, uint16_t* l) {
  __builtin_amdgcn_global_load_lds(
      (__attribute__((address_space(1))) void*)(void*)g,
      (__attribute__((address_space(3))) void*)l, 16, 0, 0);
}

// LDS swizzle (BK=64): 16B slot s holds global chunk-col (s&7)^((s>>3)&7) of
// row s>>3. Read (row r, chunk cc) -> slot r*8 + (cc ^ (r&7)).

// ------------- QKV gemm: 128x128, bn-ownership XCD map, grid 768 ------------
// x=id&7, t=id>>3: bn = x*3 + t%3 (each XCD owns 3 WqkvT stripes, 768KB
// L2-resident), bm = t/3 (A streams once per XCD). Bijective 8x3x32.
__global__ __launch_bounds__(256) void gemm_qkv(
    const uint16_t* __restrict__ A, const uint16_t* __restrict__ Bt,
    const float* __restrict__ bias, uint16_t* __restrict__ Cout,
    uint16_t* __restrict__ Vt)
{
  constexpr int BK = 64;
  __shared__ uint16_t As[128 * BK];
  __shared__ uint16_t Bs[128 * BK];
  int id = blockIdx.x;
  int x = id & 7, t = id >> 3;
  int bn = x * 3 + t % 3;
  int bm = t / 3;
  bool vblk = (bn >= 16);

  int tid  = threadIdx.x;
  int lane = tid & 63;
  int wave = tid >> 6;
  int wm = (wave >> 1) * 64, wn = (wave & 1) * 64;
  int lr = lane & 15, quad = lane >> 4;

  const uint16_t *Ag[4], *Bg[4];
  uint16_t *Al[4], *Bl[4];
#pragma unroll
  for (int s = 0; s < 4; ++s) {
    int c = tid + 256 * s;
    int r = c >> 3, q = (c & 7) ^ (r & 7);
    Ag[s] = A  + (size_t)(bm * 128 + r) * 1024 + q * 8;
    Bg[s] = Bt + (size_t)(bn * 128 + r) * 1024 + q * 8;
    Al[s] = As + c * 8;
    Bl[s] = Bs + c * 8;
  }
  const uint16_t* Fa = vblk ? Bs : As;
  const uint16_t* Fb = vblk ? As : Bs;

  f32x4 acc[4][4] = {};

  for (int k0 = 0; k0 < 1024; k0 += BK) {
    __syncthreads();
#pragma unroll
    for (int s = 0; s < 4; ++s) gload_lds16(Ag[s] + k0, Al[s]);
#pragma unroll
    for (int s = 0; s < 4; ++s) gload_lds16(Bg[s] + k0, Bl[s]);
    __syncthreads();
#pragma unroll
    for (int h = 0; h < 2; ++h) {
      short8 af[4], bfr[4];
      int cc = quad + 4 * h;
#pragma unroll
      for (int i = 0; i < 4; ++i) {
        int r = wm + i * 16 + lr;
        af[i] = *(const short8*)(&Fa[(r * 8 + (cc ^ (r & 7))) * 8]);
      }
#pragma unroll
      for (int j = 0; j < 4; ++j) {
        int r = wn + j * 16 + lr;
        bfr[j] = *(const short8*)(&Fb[(r * 8 + (cc ^ (r & 7))) * 8]);
      }
#pragma unroll
      for (int i = 0; i < 4; ++i)
#pragma unroll
        for (int j = 0; j < 4; ++j)
          acc[i][j] = __builtin_amdgcn_mfma_f32_16x16x32_bf16(af[i], bfr[j], acc[i][j], 0, 0, 0);
    }
  }

  if (vblk) {
#pragma unroll
    for (int i = 0; i < 4; ++i) {
#pragma unroll
      for (int r = 0; r < 4; ++r) {
        int n = bn * 128 + wm + i * 16 + quad * 4 + r;
        float bv = bias[n];
        uint16_t* dst = Vt + (size_t)(n - 2048) * 4096 + bm * 128;
#pragma unroll
        for (int j = 0; j < 4; ++j)
          dst[wn + j * 16 + lr] = f2bf(acc[i][j][r] + bv);
      }
    }
  } else {
    int row0 = bm * 128 + wm + quad * 4;
    int col0 = bn * 128 + wn + lr;
#pragma unroll
    for (int j = 0; j < 4; ++j) {
      int col = col0 + j * 16;
      float bv = bias[col];
#pragma unroll
      for (int i = 0; i < 4; ++i)
#pragma unroll
        for (int r = 0; r < 4; ++r)
          Cout[(size_t)(row0 + i * 16 + r) * 3072 + col] = f2bf(acc[i][j][r] + bv);
    }
  }
}

// ---------------- FFN1 gemm: 128x128, bn-quad XCD ownership, grid 1024 ------
// x=id&7, bn = x*4 + ((id>>3)&3), bm = id>>5 (bijective 8x4x32). Each XCD
// permanently owns 4 bn-stripes (1MB W1T L2-resident); A-stripes are shared
// by the 4 resident bn-blocks and stream through once per XCD.
__global__ __launch_bounds__(256) void gemm_ffn1(
    const uint16_t* __restrict__ A, const uint16_t* __restrict__ Bt,
    const float* __restrict__ bias, uint16_t* __restrict__ Cout)
{
  constexpr int BK = 64;
  __shared__ uint16_t As[128 * BK];
  __shared__ uint16_t Bs[128 * BK];
  int id = blockIdx.x;
  int bn = (id & 7) * 4 + ((id >> 3) & 3);
  int bm = id >> 5;

  int tid  = threadIdx.x;
  int lane = tid & 63;
  int wave = tid >> 6;
  int wm = (wave >> 1) * 64, wn = (wave & 1) * 64;
  int lr = lane & 15, quad = lane >> 4;

  const uint16_t *Ag[4], *Bg[4];
  uint16_t *Al[4], *Bl[4];
#pragma unroll
  for (int s = 0; s < 4; ++s) {
    int c = tid + 256 * s;
    int r = c >> 3, q = (c & 7) ^ (r & 7);
    Ag[s] = A  + (size_t)(bm * 128 + r) * 1024 + q * 8;
    Bg[s] = Bt + (size_t)(bn * 128 + r) * 1024 + q * 8;
    Al[s] = As + c * 8;
    Bl[s] = Bs + c * 8;
  }

  f32x4 acc[4][4] = {};

  for (int k0 = 0; k0 < 1024; k0 += BK) {
    __syncthreads();
#pragma unroll
    for (int s = 0; s < 4; ++s) gload_lds16(Ag[s] + k0, Al[s]);
#pragma unroll
    for (int s = 0; s < 4; ++s) gload_lds16(Bg[s] + k0, Bl[s]);
    __syncthreads();
#pragma unroll
    for (int h = 0; h < 2; ++h) {
      short8 af[4], bfr[4];
      int cc = quad + 4 * h;
#pragma unroll
      for (int i = 0; i < 4; ++i) {
        int r = wm + i * 16 + lr;
        af[i] = *(const short8*)(&As[(r * 8 + (cc ^ (r & 7))) * 8]);
      }
#pragma unroll
      for (int j = 0; j < 4; ++j) {
        int r = wn + j * 16 + lr;
        bfr[j] = *(const short8*)(&Bs[(r * 8 + (cc ^ (r & 7))) * 8]);
      }
#pragma unroll
      for (int i = 0; i < 4; ++i)
#pragma unroll
        for (int j = 0; j < 4; ++j)
          acc[i][j] = __builtin_amdgcn_mfma_f32_16x16x32_bf16(af[i], bfr[j], acc[i][j], 0, 0, 0);
    }
  }

  int row0 = bm * 128 + wm + quad * 4;
  int col0 = bn * 128 + wn + lr;
#pragma unroll
  for (int j = 0; j < 4; ++j) {
    int col = col0 + j * 16;
    float bv = bias[col];
#pragma unroll
    for (int i = 0; i < 4; ++i)
#pragma unroll
      for (int r = 0; r < 4; ++r)
        Cout[(size_t)(row0 + i * 16 + r) * 4096 + col] =
            f2bf(fmaxf(acc[i][j][r] + bv, 0.0f));
  }
}

// ---------------- causal S-gemm, 64x128 tiles, XCD-swizzled -----------------
// 1-D grid 2048: i64 = id&63 (Q-tile sharers co-XCD), bn = id>>6;
// early-exit if bn > i64>>1. Fused row-sum atomics into lvec.
__global__ __launch_bounds__(256) void gemm_s(
    const uint16_t* __restrict__ Qm, const uint16_t* __restrict__ Km,
    uint16_t* __restrict__ Sb, float* __restrict__ lvec,
    int lda, int ldb, int ldc, float scale)
{
  constexpr int BK = 64;
  __shared__ uint16_t As[64 * BK];
  __shared__ uint16_t Bs[128 * BK];
  int id = blockIdx.x;
  int i64 = id & 63, bn = id >> 6;
  if (bn > (i64 >> 1)) return;

  int tid  = threadIdx.x;
  int lane = tid & 63;
  int wave = tid >> 6;
  int wm = (wave >> 1) * 32, wn = (wave & 1) * 64;
  int lr = lane & 15, quad = lane >> 4;

  const uint16_t *Ag[2], *Bg[4];
  uint16_t *Al[2], *Bl[4];
#pragma unroll
  for (int s = 0; s < 2; ++s) {
    int c = tid + 256 * s;
    int r = c >> 3, q = (c & 7) ^ (r & 7);
    Ag[s] = Qm + (size_t)(i64 * 64 + r) * lda + q * 8;
    Al[s] = As + c * 8;
  }
#pragma unroll
  for (int s = 0; s < 4; ++s) {
    int c = tid + 256 * s;
    int r = c >> 3, q = (c & 7) ^ (r & 7);
    Bg[s] = Km + (size_t)(bn * 128 + r) * ldb + q * 8;
    Bl[s] = Bs + c * 8;
  }

  f32x4 acc[2][4] = {};

  for (int k0 = 0; k0 < 1024; k0 += BK) {
    __syncthreads();
#pragma unroll
    for (int s = 0; s < 2; ++s) gload_lds16(Ag[s] + k0, Al[s]);
#pragma unroll
    for (int s = 0; s < 4; ++s) gload_lds16(Bg[s] + k0, Bl[s]);
    __syncthreads();
#pragma unroll
    for (int h = 0; h < 2; ++h) {
      short8 af[2], bfr[4];
      int cc = quad + 4 * h;
#pragma unroll
      for (int i = 0; i < 2; ++i) {
        int r = wm + i * 16 + lr;
        af[i] = *(const short8*)(&As[(r * 8 + (cc ^ (r & 7))) * 8]);
      }
#pragma unroll
      for (int j = 0; j < 4; ++j) {
        int r = wn + j * 16 + lr;
        bfr[j] = *(const short8*)(&Bs[(r * 8 + (cc ^ (r & 7))) * 8]);
      }
#pragma unroll
      for (int i = 0; i < 2; ++i)
#pragma unroll
        for (int j = 0; j < 4; ++j)
          acc[i][j] = __builtin_amdgcn_mfma_f32_16x16x32_bf16(af[i], bfr[j], acc[i][j], 0, 0, 0);
    }
  }

  int row0 = i64 * 64 + wm + quad * 4;
  int col0 = bn * 128 + wn + lr;
#pragma unroll
  for (int i = 0; i < 2; ++i) {
#pragma unroll
    for (int r = 0; r < 4; ++r) {
      int row = row0 + i * 16 + r;
      float s = 0.0f;
#pragma unroll
      for (int j = 0; j < 4; ++j) {
        int col = col0 + j * 16;
        float v = (col <= row) ? __expf(acc[i][j][r] * scale) : 0.0f;
        Sb[(size_t)row * ldc + col] = f2bf(v);
        s += v;
      }
#pragma unroll
      for (int o = 8; o > 0; o >>= 1) s += __shfl_xor(s, o, 64);
      if (lr == 0) unsafeAtomicAdd(&lvec[row], s);
    }
  }
}

// ---------------- O-gemm: 128x128, triangular K-chunks, XCD-swizzled --------
// 1-D grid 640: id = bn*80 + p (id%8==p%8 co-XCD). p ordered LONG-FIRST.
// Opart partials bf16 (r18: verified absmax unchanged).
__global__ __launch_bounds__(256) void gemm_o(
    const uint16_t* __restrict__ Sb, const uint16_t* __restrict__ Vt,
    uint16_t* __restrict__ Opart)
{
  constexpr int BK = 64;
  __shared__ uint16_t As[128 * BK];
  __shared__ uint16_t Bs[128 * BK];
  int id = blockIdx.x;
  int bn = id / 80, p = id % 80;
  int c, bm;
  if      (p < 25) { c = 0; bm = 7 + p; }
  else if (p < 49) { c = 1; bm = 8 + (p - 25); }
  else if (p < 65) { c = 2; bm = 16 + (p - 49); }
  else if (p < 73) { c = 3; bm = 24 + (p - 65); }
  else             { c = 0; bm = 79 - p; }
  int klo = c << 10;
  int khi = (bm + 1) << 7; if (khi > ((c + 1) << 10)) khi = (c + 1) << 10;

  int tid  = threadIdx.x;
  int lane = tid & 63;
  int wave = tid >> 6;
  int wm = (wave >> 1) * 64, wn = (wave & 1) * 64;
  int lr = lane & 15, quad = lane >> 4;

  const uint16_t *Ag[4], *Bg[4];
  uint16_t *Al[4], *Bl[4];
#pragma unroll
  for (int s = 0; s < 4; ++s) {
    int cch = tid + 256 * s;
    int r = cch >> 3, q = (cch & 7) ^ (r & 7);
    Ag[s] = Sb + (size_t)(bm * 128 + r) * 4096 + q * 8;
    Bg[s] = Vt + (size_t)(bn * 128 + r) * 4096 + q * 8;
    Al[s] = As + cch * 8;
    Bl[s] = Bs + cch * 8;
  }

  f32x4 acc[4][4] = {};

  for (int k0 = klo; k0 < khi; k0 += BK) {
    __syncthreads();
#pragma unroll
    for (int s = 0; s < 4; ++s) gload_lds16(Ag[s] + k0, Al[s]);
#pragma unroll
    for (int s = 0; s < 4; ++s) gload_lds16(Bg[s] + k0, Bl[s]);
    __syncthreads();
#pragma unroll
    for (int h = 0; h < 2; ++h) {
      short8 af[4], bfr[4];
      int cc = quad + 4 * h;
#pragma unroll
      for (int i = 0; i < 4; ++i) {
        int r = wm + i * 16 + lr;
        af[i] = *(const short8*)(&As[(r * 8 + (cc ^ (r & 7))) * 8]);
      }
#pragma unroll
      for (int j = 0; j < 4; ++j) {
        int r = wn + j * 16 + lr;
        bfr[j] = *(const short8*)(&Bs[(r * 8 + (cc ^ (r & 7))) * 8]);
      }
#pragma unroll
      for (int i = 0; i < 4; ++i)
#pragma unroll
        for (int j = 0; j < 4; ++j)
          acc[i][j] = __builtin_amdgcn_mfma_f32_16x16x32_bf16(af[i], bfr[j], acc[i][j], 0, 0, 0);
    }
  }

  uint16_t* P = Opart + (size_t)c * 4194304;
  int row0 = bm * 128 + wm + quad * 4;
  int col0 = bn * 128 + wn + lr;
#pragma unroll
  for (int j = 0; j < 4; ++j)
#pragma unroll
    for (int i = 0; i < 4; ++i)
#pragma unroll
      for (int r = 0; r < 4; ++r)
        P[(size_t)(row0 + i * 16 + r) * 1024 + col0 + j * 16] = f2bf(acc[i][j][r]);
}

// ------- FFN2: 128x64 tile, dual-K-group 512-thread block, grid 512 ---------
// bn = id>>5, bm = id&31 (id%8==bm%8 co-XCD). Waves 0-3: K[0,2048);
// waves 4-7: K[2048,4096). Each group: own 24KB LDS tiles, r18-proven
// drain loop (32 lockstep iters). Combine: group1 acc -> LDS f32 (stride 65,
// conflict-free, reuses dead staging LDS), barrier, group0 adds + writes.
__global__ __launch_bounds__(512) void gemm_ffn2(
    const uint16_t* __restrict__ A, const uint16_t* __restrict__ Bt,
    const float* __restrict__ bias, float* __restrict__ Cout)
{
  constexpr int BK = 64;
  __shared__ char ldsbuf[49152];          // 2x(16KB A + 8KB B); reduce 33.3KB
  int id = blockIdx.x;
  int bn = id >> 5, bm = id & 31;

  int tid   = threadIdx.x;
  int lane  = tid & 63;
  int wave  = tid >> 6;
  int group = wave >> 2;                  // 0: K[0,2048), 1: K[2048,4096)
  int wave4 = wave & 3;
  int gtid  = tid & 255;
  int wm = (wave4 >> 1) * 64, wn = (wave4 & 1) * 32;
  int lr = lane & 15, quad = lane >> 4;

  uint16_t* Ag_l = (uint16_t*)ldsbuf + group * 8192;          // [128*64]
  uint16_t* Bg_l = (uint16_t*)(ldsbuf + 32768) + group * 4096; // [64*64]
  int kbase = group * 2048;

  const uint16_t *Ag[4], *Bg[2];
  uint16_t *Al[4], *Bl[2];
#pragma unroll
  for (int s = 0; s < 4; ++s) {
    int c = gtid + 256 * s;
    int r = c >> 3, q = (c & 7) ^ (r & 7);
    Ag[s] = A + (size_t)(bm * 128 + r) * 4096 + kbase + q * 8;
    Al[s] = Ag_l + c * 8;
  }
#pragma unroll
  for (int s = 0; s < 2; ++s) {
    int c = gtid + 256 * s;
    int r = c >> 3, q = (c & 7) ^ (r & 7);
    Bg[s] = Bt + (size_t)(bn * 64 + r) * 4096 + kbase + q * 8;
    Bl[s] = Bg_l + c * 8;
  }

  f32x4 acc[4][2] = {};

  for (int k0 = 0; k0 < 2048; k0 += BK) {
    __syncthreads();
#pragma unroll
    for (int s = 0; s < 4; ++s) gload_lds16(Ag[s] + k0, Al[s]);
#pragma unroll
    for (int s = 0; s < 2; ++s) gload_lds16(Bg[s] + k0, Bl[s]);
    __syncthreads();
#pragma unroll
    for (int h = 0; h < 2; ++h) {
      short8 af[4], bfr[2];
      int cc = quad + 4 * h;
#pragma unroll
      for (int i = 0; i < 4; ++i) {
        int r = wm + i * 16 + lr;
        af[i] = *(const short8*)(&Ag_l[(r * 8 + (cc ^ (r & 7))) * 8]);
      }
#pragma unroll
      for (int j = 0; j < 2; ++j) {
        int r = wn + j * 16 + lr;
        bfr[j] = *(const short8*)(&Bg_l[(r * 8 + (cc ^ (r & 7))) * 8]);
      }
#pragma unroll
      for (int i = 0; i < 4; ++i)
#pragma unroll
        for (int j = 0; j < 2; ++j)
          acc[i][j] = __builtin_amdgcn_mfma_f32_16x16x32_bf16(af[i], bfr[j], acc[i][j], 0, 0, 0);
    }
  }

  // combine: group1 -> LDS f32 (stride 65, conflict-free), group0 adds.
  __syncthreads();                        // all staging-LDS reads complete
  float* Lf = (float*)ldsbuf;             // 128*65*4 = 33280B
  if (group == 1) {
#pragma unroll
    for (int i = 0; i < 4; ++i)
#pragma unroll
      for (int r = 0; r < 4; ++r) {
        int lrow = wm + i * 16 + quad * 4 + r;
#pragma unroll
        for (int j = 0; j < 2; ++j)
          Lf[lrow * 65 + wn + j * 16 + lr] = acc[i][j][r];
      }
  }
  __syncthreads();
  if (group == 0) {
    int row0 = bm * 128 + wm + quad * 4;
    int col0 = bn * 64 + wn + lr;
#pragma unroll
    for (int j = 0; j < 2; ++j) {
      int col = col0 + j * 16;
      float bv = bias[col];
#pragma unroll
      for (int i = 0; i < 4; ++i)
#pragma unroll
        for (int r = 0; r < 4; ++r) {
          int lrow = wm + i * 16 + quad * 4 + r;
          Cout[(size_t)(row0 + i * 16 + r) * 1024 + col] =
              acc[i][j][r] + Lf[lrow * 65 + wn + j * 16 + lr] + bv;
        }
    }
  }
}

// ---------------- reductions ------------------------------------------------
__device__ __forceinline__ float block_sum(float v, float* red) {
#pragma unroll
  for (int o = 32; o > 0; o >>= 1) v += __shfl_xor(v, o, 64);
  if ((threadIdx.x & 63) == 0) red[threadIdx.x >> 6] = v;
  __syncthreads();
  v = red[0] + red[1] + red[2] + red[3];
  __syncthreads();
  return v;
}

// ------ O-chunk bf16 partials reduce /l + residual + LayerNorm -> bf16 ------
__global__ __launch_bounds__(256) void add_layernorm(
    const uint16_t* __restrict__ P, const float* __restrict__ l,
    const float* __restrict__ emb, const float* __restrict__ gamma,
    const float* __restrict__ beta, uint16_t* __restrict__ xB)
{
  __shared__ float red[4];
  int i = blockIdx.x, tid = threadIdx.x;
  float inv_l = 1.0f / l[i];
  int nc = (i >> 10) + 1;
  float s0 = 0.0f, s1 = 0.0f, s2 = 0.0f, s3 = 0.0f;
  for (int c = 0; c < nc; ++c) {
    ushort4 a = ((const ushort4*)(P + (size_t)c * 4194304 + (size_t)i * 1024))[tid];
    s0 += bf2f(a.x); s1 += bf2f(a.y); s2 += bf2f(a.z); s3 += bf2f(a.w);
  }
  float4 b = ((const float4*)(emb + (size_t)i * 1024))[tid];
  float x0 = s0 * inv_l + b.x, x1 = s1 * inv_l + b.y;
  float x2 = s2 * inv_l + b.z, x3 = s3 * inv_l + b.w;
  float mu = block_sum(x0 + x1 + x2 + x3, red) * (1.0f / 1024.0f);
  float d0 = x0 - mu, d1 = x1 - mu, d2 = x2 - mu, d3 = x3 - mu;
  float var = block_sum(d0 * d0 + d1 * d1 + d2 * d2 + d3 * d3, red) * (1.0f / 1024.0f);
  float rs = rsqrtf(var + 1e-5f);
  float4 g  = ((const float4*)gamma)[tid];
  float4 be = ((const float4*)beta)[tid];
  ushort4 o;
  o.x = f2bf(d0 * rs * g.x + be.x);
  o.y = f2bf(d1 * rs * g.y + be.y);
  o.z = f2bf(d2 * rs * g.z + be.z);
  o.w = f2bf(d3 * rs * g.w + be.w);
  ((ushort4*)(xB + (size_t)i * 1024))[tid] = o;
}

// ---------------- prep: all casts/transposes/bias/init in one launch --------
__global__ __launch_bounds__(256) void prep(
    const float* __restrict__ emb, const float* __restrict__ Wq,
    const float* __restrict__ Wk, const float* __restrict__ Wv,
    const float* __restrict__ W1, const float* __restrict__ W2,
    const float* __restrict__ bq, const float* __restrict__ bk,
    const float* __restrict__ bv, uint16_t* __restrict__ embB,
    uint16_t* __restrict__ WqkvT, uint16_t* __restrict__ W1T,
    uint16_t* __restrict__ W2T, float* __restrict__ bqkv,
    float* __restrict__ lvec)
{
  __shared__ float tile[32][33];
  int b = blockIdx.x, tid = threadIdx.x;
  if (b < 4096) {                        // emb cast
    int idx = b * 256 + tid;
    float4 v = ((const float4*)emb)[idx];
    ushort4 o; o.x = f2bf(v.x); o.y = f2bf(v.y); o.z = f2bf(v.z); o.w = f2bf(v.w);
    ((ushort4*)embB)[idx] = o;
    return;
  }
  int tx = tid & 31, ty = tid >> 5;
  if (b < 7168) {                        // Wq/Wk/Wv -> WqkvT
    int local = b - 4096;
    const float* in = (local < 1024) ? Wq : (local < 2048) ? Wk : Wv;
    uint16_t* o = WqkvT + (size_t)(local >> 10) * 1048576;
    int rem = local & 1023;
    int r0 = (rem >> 5) * 32, c0 = (rem & 31) * 32;
#pragma unroll
    for (int r = 0; r < 32; r += 8)
      tile[ty + r][tx] = in[(size_t)(r0 + ty + r) * 1024 + c0 + tx];
    __syncthreads();
#pragma unroll
    for (int r = 0; r < 32; r += 8)
      o[(size_t)(c0 + ty + r) * 1024 + r0 + tx] = f2bf(tile[tx][ty + r]);
    return;
  }
  if (b < 11264) {                       // W1 -> W1T
    int local = b - 7168;
    int c0 = (local & 127) * 32, r0 = (local >> 7) * 32;
#pragma unroll
    for (int r = 0; r < 32; r += 8)
      tile[ty + r][tx] = W1[(size_t)(r0 + ty + r) * 4096 + c0 + tx];
    __syncthreads();
#pragma unroll
    for (int r = 0; r < 32; r += 8)
      W1T[(size_t)(c0 + ty + r) * 1024 + r0 + tx] = f2bf(tile[tx][ty + r]);
    return;
  }
  if (b < 15360) {                       // W2 -> W2T
    int local = b - 11264;
    int c0 = (local & 31) * 32, r0 = (local >> 5) * 32;
#pragma unroll
    for (int r = 0; r < 32; r += 8)
      tile[ty + r][tx] = W2[(size_t)(r0 + ty + r) * 1024 + c0 + tx];
    __syncthreads();
#pragma unroll
    for (int r = 0; r < 32; r += 8)
      W2T[(size_t)(c0 + ty + r) * 4096 + r0 + tx] = f2bf(tile[tx][ty + r]);
    return;
  }
  if (b < 15372) {                       // pack bq|bk|bv
    int i = (b - 15360) * 256 + tid;
    bqkv[i] = (i < 1024) ? bq[i] : (i < 2048) ? bk[i - 1024] : bv[i - 2048];
    return;
  }
  {                                      // lvec = 0
#pragma unroll
    for (int i = tid; i < 4096; i += 256) lvec[i] = 0.0f;
  }
}

// ---------------- launcher --------------------------------------------------
extern "C" void kernel_launch(void* const* d_in, const int* in_sizes, int n_in,
                              void* d_out, int out_size, void* d_ws, size_t ws_size,
                              hipStream_t stream) {
  const float* emb   = (const float*)d_in[0];
  const float* Wq    = (const float*)d_in[1];
  const float* bq    = (const float*)d_in[2];
  const float* Wk    = (const float*)d_in[3];
  const float* bk    = (const float*)d_in[4];
  const float* Wv    = (const float*)d_in[5];
  const float* bv    = (const float*)d_in[6];
  const float* gamma = (const float*)d_in[7];
  const float* beta  = (const float*)d_in[8];
  const float* W1    = (const float*)d_in[9];
  const float* b1    = (const float*)d_in[10];
  const float* W2    = (const float*)d_in[11];
  const float* b2    = (const float*)d_in[12];

  char* w = (char*)d_ws;
  const size_t MB = 1ull << 20;
  uint16_t* embB  = (uint16_t*)(w + 0 * MB);    // [4096,1024] bf16
  uint16_t* WqkvT = (uint16_t*)(w + 8 * MB);    // [3072,1024]
  uint16_t* W1T   = (uint16_t*)(w + 14 * MB);   // [4096,1024]
  uint16_t* W2T   = (uint16_t*)(w + 22 * MB);   // [1024,4096]
  float*    bqkv  = (float*)(w + 30 * MB);      // [3072]
  float*    lvec  = (float*)(w + 30 * MB + 65536); // [4096]
  uint16_t* QKVb  = (uint16_t*)(w + 31 * MB);   // [4096,3072] (V cols unused)
  uint16_t* Vt    = (uint16_t*)(w + 55 * MB);   // [1024,4096]
  uint16_t* Sb    = (uint16_t*)(w + 63 * MB);   // [4096,4096] bf16 exp(S)
  uint16_t* hB    = (uint16_t*)(w + 63 * MB);   // reuses Sb (dead after O)
  uint16_t* Opart = (uint16_t*)(w + 95 * MB);   // [4][4096,1024] bf16 chunks
  uint16_t* xB    = (uint16_t*)(w + 0 * MB);    // reuses embB
  // total ws requirement: 127 MB

  prep<<<15373, 256, 0, stream>>>(emb, Wq, Wk, Wv, W1, W2, bq, bk, bv,
                                  embB, WqkvT, W1T, W2T, bqkv, lvec);

  // fused QKV: Q,K -> QKVb; V -> Vt via operand-swapped MFMA; bn-owned XCDs
  gemm_qkv<<<768, 256, 0, stream>>>(embB, WqkvT, bqkv, QKVb, Vt);
  const uint16_t* Qb = QKVb;
  const uint16_t* Kb = QKVb + 1024;

  // exp(S): 64x128 causal tiles, XCD-swizzled 2048-slot launch
  gemm_s<<<2048, 256, 0, stream>>>(Qb, Kb, Sb, lvec, 3072, 3072, 4096, 0.03125f);

  // O' = exp(S) @ V: 128x128 triangular K-chunks, XCD-swizzled, long-first
  gemm_o<<<640, 256, 0, stream>>>(Sb, Vt, Opart);

  // reduce O bf16 chunk-partials, /l, + residual, LayerNorm -> xB
  add_layernorm<<<4096, 256, 0, stream>>>(Opart, lvec, emb, gamma, beta, xB);

  // FFN1: bn-quad XCD ownership (1MB W1T L2-resident per XCD)
  gemm_ffn1<<<1024, 256, 0, stream>>>(xB, W1T, b1, hB);

  // FFN2: dual-K-group 512-thread blocks (16 waves/CU at 128x64-tile bytes)
  gemm_ffn2<<<512, 512, 0, stream>>>(hB, W2T, b2, (float*)d_out);
}

// Round 14
// 307.912 us; speedup vs baseline: 1.0408x; 1.0012x over previous
//
#include <hip/hip_runtime.h>
#include <stdint.h>

// Round 24: ffn1 gets the counted-vmcnt depth-2 pipeline (r22-proven
// structure, passed correctness twice). Diagnosis: ffn1 at 48us runs
// staging at only 11 TB/s (vs ffn2's 20) with serialized
// stage(2340cyc)+compute(620cyc) per K-step at 4-way TLP — exposed-latency
// regime, exactly where counted-vmcnt has headroom (r19's null was at the
// rate ceiling; ffn1 is 2x below it). 128x128, BK=64, 8 loads/stage,
// prologue 16 outstanding, steady vmcnt(8), raw barriers, peeled tail.
// LDS 64KB -> 2 blocks/CU. ffn2 frozen at r23 dual-K-group (48.0, best
// of 5 forms). Everything else frozen. ws: 127 MB.

using short8 = __attribute__((ext_vector_type(8))) short;
using f32x4  = __attribute__((ext_vector_type(4))) float;

__device__ __forceinline__ uint16_t f2bf(float f) {
  uint32_t u = __builtin_bit_cast(uint32_t, f);
  u += 0x7FFFu + ((u >> 16) & 1u);        // RNE, inputs are finite
  return (uint16_t)(u >> 16);
}

__device__ __forceinline__ float bf2f(uint16_t u) {
  return __builtin_bit_cast(float, (uint32_t)u << 16);
}

__device__ __forceinline__ void gload_lds16(const uint16_t* g, uint16_t* l) {
  __builtin_amdgcn_global_load_lds(
      (__attribute__((address_space(1))) void*)(void*)g,
      (__attribute__((address_space(3))) void*)l, 16, 0, 0);
}

// LDS swizzle (BK=64): 16B slot s holds global chunk-col (s&7)^((s>>3)&7) of
// row s>>3. Read (row r, chunk cc) -> slot r*8 + (cc ^ (r&7)).

// ------------- QKV gemm: 128x128, bn-ownership XCD map, grid 768 ------------
// x=id&7, t=id>>3: bn = x*3 + t%3 (each XCD owns 3 WqkvT stripes, 768KB
// L2-resident), bm = t/3 (A streams once per XCD). Bijective 8x3x32.
__global__ __launch_bounds__(256) void gemm_qkv(
    const uint16_t* __restrict__ A, const uint16_t* __restrict__ Bt,
    const float* __restrict__ bias, uint16_t* __restrict__ Cout,
    uint16_t* __restrict__ Vt)
{
  constexpr int BK = 64;
  __shared__ uint16_t As[128 * BK];
  __shared__ uint16_t Bs[128 * BK];
  int id = blockIdx.x;
  int x = id & 7, t = id >> 3;
  int bn = x * 3 + t % 3;
  int bm = t / 3;
  bool vblk = (bn >= 16);

  int tid  = threadIdx.x;
  int lane = tid & 63;
  int wave = tid >> 6;
  int wm = (wave >> 1) * 64, wn = (wave & 1) * 64;
  int lr = lane & 15, quad = lane >> 4;

  const uint16_t *Ag[4], *Bg[4];
  uint16_t *Al[4], *Bl[4];
#pragma unroll
  for (int s = 0; s < 4; ++s) {
    int c = tid + 256 * s;
    int r = c >> 3, q = (c & 7) ^ (r & 7);
    Ag[s] = A  + (size_t)(bm * 128 + r) * 1024 + q * 8;
    Bg[s] = Bt + (size_t)(bn * 128 + r) * 1024 + q * 8;
    Al[s] = As + c * 8;
    Bl[s] = Bs + c * 8;
  }
  const uint16_t* Fa = vblk ? Bs : As;
  const uint16_t* Fb = vblk ? As : Bs;

  f32x4 acc[4][4] = {};

  for (int k0 = 0; k0 < 1024; k0 += BK) {
    __syncthreads();
#pragma unroll
    for (int s = 0; s < 4; ++s) gload_lds16(Ag[s] + k0, Al[s]);
#pragma unroll
    for (int s = 0; s < 4; ++s) gload_lds16(Bg[s] + k0, Bl[s]);
    __syncthreads();
#pragma unroll
    for (int h = 0; h < 2; ++h) {
      short8 af[4], bfr[4];
      int cc = quad + 4 * h;
#pragma unroll
      for (int i = 0; i < 4; ++i) {
        int r = wm + i * 16 + lr;
        af[i] = *(const short8*)(&Fa[(r * 8 + (cc ^ (r & 7))) * 8]);
      }
#pragma unroll
      for (int j = 0; j < 4; ++j) {
        int r = wn + j * 16 + lr;
        bfr[j] = *(const short8*)(&Fb[(r * 8 + (cc ^ (r & 7))) * 8]);
      }
#pragma unroll
      for (int i = 0; i < 4; ++i)
#pragma unroll
        for (int j = 0; j < 4; ++j)
          acc[i][j] = __builtin_amdgcn_mfma_f32_16x16x32_bf16(af[i], bfr[j], acc[i][j], 0, 0, 0);
    }
  }

  if (vblk) {
#pragma unroll
    for (int i = 0; i < 4; ++i) {
#pragma unroll
      for (int r = 0; r < 4; ++r) {
        int n = bn * 128 + wm + i * 16 + quad * 4 + r;
        float bv = bias[n];
        uint16_t* dst = Vt + (size_t)(n - 2048) * 4096 + bm * 128;
#pragma unroll
        for (int j = 0; j < 4; ++j)
          dst[wn + j * 16 + lr] = f2bf(acc[i][j][r] + bv);
      }
    }
  } else {
    int row0 = bm * 128 + wm + quad * 4;
    int col0 = bn * 128 + wn + lr;
#pragma unroll
    for (int j = 0; j < 4; ++j) {
      int col = col0 + j * 16;
      float bv = bias[col];
#pragma unroll
      for (int i = 0; i < 4; ++i)
#pragma unroll
        for (int r = 0; r < 4; ++r)
          Cout[(size_t)(row0 + i * 16 + r) * 3072 + col] = f2bf(acc[i][j][r] + bv);
    }
  }
}

// ------- FFN1: 128x128, counted-vmcnt depth-2 pipeline, quad XCD map --------
// x=id&7, bn = x*4 + ((id>>3)&3), bm = id>>5 (bijective 8x4x32).
// STAGE = 8 loads (4 A + 4 B, FIFO); depth-2 -> 16 outstanding, steady
// s_waitcnt vmcnt(8), raw s_barrier pairs, peeled 2-step tail (8 -> 0).
// LDS 2x32KB = 64KB -> 2 blocks/CU; pipeline overlaps staging w/ compute.
__global__ __launch_bounds__(256) void gemm_ffn1(
    const uint16_t* __restrict__ A, const uint16_t* __restrict__ Bt,
    const float* __restrict__ bias, uint16_t* __restrict__ Cout)
{
  constexpr int BK = 64;
  __shared__ uint16_t AsB[2][128 * BK];
  __shared__ uint16_t BsB[2][128 * BK];
  int id = blockIdx.x;
  int bn = (id & 7) * 4 + ((id >> 3) & 3);
  int bm = id >> 5;

  int tid  = threadIdx.x;
  int lane = tid & 63;
  int wave = tid >> 6;
  int wm = (wave >> 1) * 64, wn = (wave & 1) * 64;
  int lr = lane & 15, quad = lane >> 4;

  const uint16_t *Ag[4], *Bg[4];
  int off[4];
#pragma unroll
  for (int s = 0; s < 4; ++s) {
    int c = tid + 256 * s;
    int r = c >> 3, q = (c & 7) ^ (r & 7);
    Ag[s] = A  + (size_t)(bm * 128 + r) * 1024 + q * 8;
    Bg[s] = Bt + (size_t)(bn * 128 + r) * 1024 + q * 8;
    off[s] = c * 8;
  }

  f32x4 acc[4][4] = {};

  // 8 loads per thread per STAGE, FIFO order A0..A3,B0..B3.
  auto STAGE = [&](uint16_t* Ab, uint16_t* Bb, int k0) {
#pragma unroll
    for (int s = 0; s < 4; ++s) gload_lds16(Ag[s] + k0, Ab + off[s]);
#pragma unroll
    for (int s = 0; s < 4; ++s) gload_lds16(Bg[s] + k0, Bb + off[s]);
  };
  auto COMP = [&](const uint16_t* Ab, const uint16_t* Bb) {
#pragma unroll
    for (int h = 0; h < 2; ++h) {
      short8 af[4], bfr[4];
      int cc = quad + 4 * h;
#pragma unroll
      for (int i = 0; i < 4; ++i) {
        int r = wm + i * 16 + lr;
        af[i] = *(const short8*)(&Ab[(r * 8 + (cc ^ (r & 7))) * 8]);
      }
#pragma unroll
      for (int j = 0; j < 4; ++j) {
        int r = wn + j * 16 + lr;
        bfr[j] = *(const short8*)(&Bb[(r * 8 + (cc ^ (r & 7))) * 8]);
      }
#pragma unroll
      for (int i = 0; i < 4; ++i)
#pragma unroll
        for (int j = 0; j < 4; ++j)
          acc[i][j] = __builtin_amdgcn_mfma_f32_16x16x32_bf16(af[i], bfr[j], acc[i][j], 0, 0, 0);
    }
  };

  uint16_t *cA = &AsB[0][0], *cB = &BsB[0][0];
  uint16_t *nA = &AsB[1][0], *nB = &BsB[1][0];

  STAGE(cA, cB, 0);        // step 0 (oldest 8)
  STAGE(nA, nB, BK);       // step 1 — 16 outstanding

  for (int t = 0; t < 14; ++t) {
    asm volatile("s_waitcnt vmcnt(8)" ::: "memory");  // cur buffer complete
    __builtin_amdgcn_s_barrier();                     // ...for ALL waves
    COMP(cA, cB);
    __builtin_amdgcn_s_barrier();                     // all done reading cur
    STAGE(cA, cB, (t + 2) * BK);                      // overwrite cur for t+2
    uint16_t* tp;
    tp = cA; cA = nA; nA = tp;
    tp = cB; cB = nB; nB = tp;
  }
  // step 14: outstanding = stage14(8, oldest) + stage15(8)
  asm volatile("s_waitcnt vmcnt(8)" ::: "memory");
  __builtin_amdgcn_s_barrier();
  COMP(cA, cB);
  // step 15: drain the final 8
  asm volatile("s_waitcnt vmcnt(0)" ::: "memory");
  __builtin_amdgcn_s_barrier();
  COMP(nA, nB);

  int row0 = bm * 128 + wm + quad * 4;
  int col0 = bn * 128 + wn + lr;
#pragma unroll
  for (int j = 0; j < 4; ++j) {
    int col = col0 + j * 16;
    float bv = bias[col];
#pragma unroll
    for (int i = 0; i < 4; ++i)
#pragma unroll
      for (int r = 0; r < 4; ++r)
        Cout[(size_t)(row0 + i * 16 + r) * 4096 + col] =
            f2bf(fmaxf(acc[i][j][r] + bv, 0.0f));
  }
}

// ---------------- causal S-gemm, 64x128 tiles, XCD-swizzled -----------------
// 1-D grid 2048: i64 = id&63 (Q-tile sharers co-XCD), bn = id>>6;
// early-exit if bn > i64>>1. Fused row-sum atomics into lvec.
__global__ __launch_bounds__(256) void gemm_s(
    const uint16_t* __restrict__ Qm, const uint16_t* __restrict__ Km,
    uint16_t* __restrict__ Sb, float* __restrict__ lvec,
    int lda, int ldb, int ldc, float scale)
{
  constexpr int BK = 64;
  __shared__ uint16_t As[64 * BK];
  __shared__ uint16_t Bs[128 * BK];
  int id = blockIdx.x;
  int i64 = id & 63, bn = id >> 6;
  if (bn > (i64 >> 1)) return;

  int tid  = threadIdx.x;
  int lane = tid & 63;
  int wave = tid >> 6;
  int wm = (wave >> 1) * 32, wn = (wave & 1) * 64;
  int lr = lane & 15, quad = lane >> 4;

  const uint16_t *Ag[2], *Bg[4];
  uint16_t *Al[2], *Bl[4];
#pragma unroll
  for (int s = 0; s < 2; ++s) {
    int c = tid + 256 * s;
    int r = c >> 3, q = (c & 7) ^ (r & 7);
    Ag[s] = Qm + (size_t)(i64 * 64 + r) * lda + q * 8;
    Al[s] = As + c * 8;
  }
#pragma unroll
  for (int s = 0; s < 4; ++s) {
    int c = tid + 256 * s;
    int r = c >> 3, q = (c & 7) ^ (r & 7);
    Bg[s] = Km + (size_t)(bn * 128 + r) * ldb + q * 8;
    Bl[s] = Bs + c * 8;
  }

  f32x4 acc[2][4] = {};

  for (int k0 = 0; k0 < 1024; k0 += BK) {
    __syncthreads();
#pragma unroll
    for (int s = 0; s < 2; ++s) gload_lds16(Ag[s] + k0, Al[s]);
#pragma unroll
    for (int s = 0; s < 4; ++s) gload_lds16(Bg[s] + k0, Bl[s]);
    __syncthreads();
#pragma unroll
    for (int h = 0; h < 2; ++h) {
      short8 af[2], bfr[4];
      int cc = quad + 4 * h;
#pragma unroll
      for (int i = 0; i < 2; ++i) {
        int r = wm + i * 16 + lr;
        af[i] = *(const short8*)(&As[(r * 8 + (cc ^ (r & 7))) * 8]);
      }
#pragma unroll
      for (int j = 0; j < 4; ++j) {
        int r = wn + j * 16 + lr;
        bfr[j] = *(const short8*)(&Bs[(r * 8 + (cc ^ (r & 7))) * 8]);
      }
#pragma unroll
      for (int i = 0; i < 2; ++i)
#pragma unroll
        for (int j = 0; j < 4; ++j)
          acc[i][j] = __builtin_amdgcn_mfma_f32_16x16x32_bf16(af[i], bfr[j], acc[i][j], 0, 0, 0);
    }
  }

  int row0 = i64 * 64 + wm + quad * 4;
  int col0 = bn * 128 + wn + lr;
#pragma unroll
  for (int i = 0; i < 2; ++i) {
#pragma unroll
    for (int r = 0; r < 4; ++r) {
      int row = row0 + i * 16 + r;
      float s = 0.0f;
#pragma unroll
      for (int j = 0; j < 4; ++j) {
        int col = col0 + j * 16;
        float v = (col <= row) ? __expf(acc[i][j][r] * scale) : 0.0f;
        Sb[(size_t)row * ldc + col] = f2bf(v);
        s += v;
      }
#pragma unroll
      for (int o = 8; o > 0; o >>= 1) s += __shfl_xor(s, o, 64);
      if (lr == 0) unsafeAtomicAdd(&lvec[row], s);
    }
  }
}

// ---------------- O-gemm: 128x128, triangular K-chunks, XCD-swizzled --------
// 1-D grid 640: id = bn*80 + p (id%8==p%8 co-XCD). p ordered LONG-FIRST.
// Opart partials bf16 (r18: verified absmax unchanged).
__global__ __launch_bounds__(256) void gemm_o(
    const uint16_t* __restrict__ Sb, const uint16_t* __restrict__ Vt,
    uint16_t* __restrict__ Opart)
{
  constexpr int BK = 64;
  __shared__ uint16_t As[128 * BK];
  __shared__ uint16_t Bs[128 * BK];
  int id = blockIdx.x;
  int bn = id / 80, p = id % 80;
  int c, bm;
  if      (p < 25) { c = 0; bm = 7 + p; }
  else if (p < 49) { c = 1; bm = 8 + (p - 25); }
  else if (p < 65) { c = 2; bm = 16 + (p - 49); }
  else if (p < 73) { c = 3; bm = 24 + (p - 65); }
  else             { c = 0; bm = 79 - p; }
  int klo = c << 10;
  int khi = (bm + 1) << 7; if (khi > ((c + 1) << 10)) khi = (c + 1) << 10;

  int tid  = threadIdx.x;
  int lane = tid & 63;
  int wave = tid >> 6;
  int wm = (wave >> 1) * 64, wn = (wave & 1) * 64;
  int lr = lane & 15, quad = lane >> 4;

  const uint16_t *Ag[4], *Bg[4];
  uint16_t *Al[4], *Bl[4];
#pragma unroll
  for (int s = 0; s < 4; ++s) {
    int cch = tid + 256 * s;
    int r = cch >> 3, q = (cch & 7) ^ (r & 7);
    Ag[s] = Sb + (size_t)(bm * 128 + r) * 4096 + q * 8;
    Bg[s] = Vt + (size_t)(bn * 128 + r) * 4096 + q * 8;
    Al[s] = As + cch * 8;
    Bl[s] = Bs + cch * 8;
  }

  f32x4 acc[4][4] = {};

  for (int k0 = klo; k0 < khi; k0 += BK) {
    __syncthreads();
#pragma unroll
    for (int s = 0; s < 4; ++s) gload_lds16(Ag[s] + k0, Al[s]);
#pragma unroll
    for (int s = 0; s < 4; ++s) gload_lds16(Bg[s] + k0, Bl[s]);
    __syncthreads();
#pragma unroll
    for (int h = 0; h < 2; ++h) {
      short8 af[4], bfr[4];
      int cc = quad + 4 * h;
#pragma unroll
      for (int i = 0; i < 4; ++i) {
        int r = wm + i * 16 + lr;
        af[i] = *(const short8*)(&As[(r * 8 + (cc ^ (r & 7))) * 8]);
      }
#pragma unroll
      for (int j = 0; j < 4; ++j) {
        int r = wn + j * 16 + lr;
        bfr[j] = *(const short8*)(&Bs[(r * 8 + (cc ^ (r & 7))) * 8]);
      }
#pragma unroll
      for (int i = 0; i < 4; ++i)
#pragma unroll
        for (int j = 0; j < 4; ++j)
          acc[i][j] = __builtin_amdgcn_mfma_f32_16x16x32_bf16(af[i], bfr[j], acc[i][j], 0, 0, 0);
    }
  }

  uint16_t* P = Opart + (size_t)c * 4194304;
  int row0 = bm * 128 + wm + quad * 4;
  int col0 = bn * 128 + wn + lr;
#pragma unroll
  for (int j = 0; j < 4; ++j)
#pragma unroll
    for (int i = 0; i < 4; ++i)
#pragma unroll
      for (int r = 0; r < 4; ++r)
        P[(size_t)(row0 + i * 16 + r) * 1024 + col0 + j * 16] = f2bf(acc[i][j][r]);
}

// ------- FFN2: 128x64 tile, dual-K-group 512-thread block, grid 512 ---------
// bn = id>>5, bm = id&31 (id%8==bm%8 co-XCD). Waves 0-3: K[0,2048);
// waves 4-7: K[2048,4096). Each group: own 24KB LDS tiles, r18-proven
// drain loop (32 lockstep iters). Combine: group1 acc -> LDS f32 (stride 65,
// conflict-free-ish), barrier, group0 adds + writes. (frozen: best of 5)
__global__ __launch_bounds__(512) void gemm_ffn2(
    const uint16_t* __restrict__ A, const uint16_t* __restrict__ Bt,
    const float* __restrict__ bias, float* __restrict__ Cout)
{
  constexpr int BK = 64;
  __shared__ char ldsbuf[49152];          // 2x(16KB A + 8KB B); reduce 33.3KB
  int id = blockIdx.x;
  int bn = id >> 5, bm = id & 31;

  int tid   = threadIdx.x;
  int lane  = tid & 63;
  int wave  = tid >> 6;
  int group = wave >> 2;                  // 0: K[0,2048), 1: K[2048,4096)
  int wave4 = wave & 3;
  int gtid  = tid & 255;
  int wm = (wave4 >> 1) * 64, wn = (wave4 & 1) * 32;
  int lr = lane & 15, quad = lane >> 4;

  uint16_t* Ag_l = (uint16_t*)ldsbuf + group * 8192;          // [128*64]
  uint16_t* Bg_l = (uint16_t*)(ldsbuf + 32768) + group * 4096; // [64*64]
  int kbase = group * 2048;

  const uint16_t *Ag[4], *Bg[2];
  uint16_t *Al[4], *Bl[2];
#pragma unroll
  for (int s = 0; s < 4; ++s) {
    int c = gtid + 256 * s;
    int r = c >> 3, q = (c & 7) ^ (r & 7);
    Ag[s] = A + (size_t)(bm * 128 + r) * 4096 + kbase + q * 8;
    Al[s] = Ag_l + c * 8;
  }
#pragma unroll
  for (int s = 0; s < 2; ++s) {
    int c = gtid + 256 * s;
    int r = c >> 3, q = (c & 7) ^ (r & 7);
    Bg[s] = Bt + (size_t)(bn * 64 + r) * 4096 + kbase + q * 8;
    Bl[s] = Bg_l + c * 8;
  }

  f32x4 acc[4][2] = {};

  for (int k0 = 0; k0 < 2048; k0 += BK) {
    __syncthreads();
#pragma unroll
    for (int s = 0; s < 4; ++s) gload_lds16(Ag[s] + k0, Al[s]);
#pragma unroll
    for (int s = 0; s < 2; ++s) gload_lds16(Bg[s] + k0, Bl[s]);
    __syncthreads();
#pragma unroll
    for (int h = 0; h < 2; ++h) {
      short8 af[4], bfr[2];
      int cc = quad + 4 * h;
#pragma unroll
      for (int i = 0; i < 4; ++i) {
        int r = wm + i * 16 + lr;
        af[i] = *(const short8*)(&Ag_l[(r * 8 + (cc ^ (r & 7))) * 8]);
      }
#pragma unroll
      for (int j = 0; j < 2; ++j) {
        int r = wn + j * 16 + lr;
        bfr[j] = *(const short8*)(&Bg_l[(r * 8 + (cc ^ (r & 7))) * 8]);
      }
#pragma unroll
      for (int i = 0; i < 4; ++i)
#pragma unroll
        for (int j = 0; j < 2; ++j)
          acc[i][j] = __builtin_amdgcn_mfma_f32_16x16x32_bf16(af[i], bfr[j], acc[i][j], 0, 0, 0);
    }
  }

  // combine: group1 -> LDS f32 (stride 65), group0 adds.
  __syncthreads();                        // all staging-LDS reads complete
  float* Lf = (float*)ldsbuf;             // 128*65*4 = 33280B
  if (group == 1) {
#pragma unroll
    for (int i = 0; i < 4; ++i)
#pragma unroll
      for (int r = 0; r < 4; ++r) {
        int lrow = wm + i * 16 + quad * 4 + r;
#pragma unroll
        for (int j = 0; j < 2; ++j)
          Lf[lrow * 65 + wn + j * 16 + lr] = acc[i][j][r];
      }
  }
  __syncthreads();
  if (group == 0) {
    int row0 = bm * 128 + wm + quad * 4;
    int col0 = bn * 64 + wn + lr;
#pragma unroll
    for (int j = 0; j < 2; ++j) {
      int col = col0 + j * 16;
      float bv = bias[col];
#pragma unroll
      for (int i = 0; i < 4; ++i)
#pragma unroll
        for (int r = 0; r < 4; ++r) {
          int lrow = wm + i * 16 + quad * 4 + r;
          Cout[(size_t)(row0 + i * 16 + r) * 1024 + col] =
              acc[i][j][r] + Lf[lrow * 65 + wn + j * 16 + lr] + bv;
        }
    }
  }
}

// ---------------- reductions ------------------------------------------------
__device__ __forceinline__ float block_sum(float v, float* red) {
#pragma unroll
  for (int o = 32; o > 0; o >>= 1) v += __shfl_xor(v, o, 64);
  if ((threadIdx.x & 63) == 0) red[threadIdx.x >> 6] = v;
  __syncthreads();
  v = red[0] + red[1] + red[2] + red[3];
  __syncthreads();
  return v;
}

// ------ O-chunk bf16 partials reduce /l + residual + LayerNorm -> bf16 ------
__global__ __launch_bounds__(256) void add_layernorm(
    const uint16_t* __restrict__ P, const float* __restrict__ l,
    const float* __restrict__ emb, const float* __restrict__ gamma,
    const float* __restrict__ beta, uint16_t* __restrict__ xB)
{
  __shared__ float red[4];
  int i = blockIdx.x, tid = threadIdx.x;
  float inv_l = 1.0f / l[i];
  int nc = (i >> 10) + 1;
  float s0 = 0.0f, s1 = 0.0f, s2 = 0.0f, s3 = 0.0f;
  for (int c = 0; c < nc; ++c) {
    ushort4 a = ((const ushort4*)(P + (size_t)c * 4194304 + (size_t)i * 1024))[tid];
    s0 += bf2f(a.x); s1 += bf2f(a.y); s2 += bf2f(a.z); s3 += bf2f(a.w);
  }
  float4 b = ((const float4*)(emb + (size_t)i * 1024))[tid];
  float x0 = s0 * inv_l + b.x, x1 = s1 * inv_l + b.y;
  float x2 = s2 * inv_l + b.z, x3 = s3 * inv_l + b.w;
  float mu = block_sum(x0 + x1 + x2 + x3, red) * (1.0f / 1024.0f);
  float d0 = x0 - mu, d1 = x1 - mu, d2 = x2 - mu, d3 = x3 - mu;
  float var = block_sum(d0 * d0 + d1 * d1 + d2 * d2 + d3 * d3, red) * (1.0f / 1024.0f);
  float rs = rsqrtf(var + 1e-5f);
  float4 g  = ((const float4*)gamma)[tid];
  float4 be = ((const float4*)beta)[tid];
  ushort4 o;
  o.x = f2bf(d0 * rs * g.x + be.x);
  o.y = f2bf(d1 * rs * g.y + be.y);
  o.z = f2bf(d2 * rs * g.z + be.z);
  o.w = f2bf(d3 * rs * g.w + be.w);
  ((ushort4*)(xB + (size_t)i * 1024))[tid] = o;
}

// ---------------- prep: all casts/transposes/bias/init in one launch --------
__global__ __launch_bounds__(256) void prep(
    const float* __restrict__ emb, const float* __restrict__ Wq,
    const float* __restrict__ Wk, const float* __restrict__ Wv,
    const float* __restrict__ W1, const float* __restrict__ W2,
    const float* __restrict__ bq, const float* __restrict__ bk,
    const float* __restrict__ bv, uint16_t* __restrict__ embB,
    uint16_t* __restrict__ WqkvT, uint16_t* __restrict__ W1T,
    uint16_t* __restrict__ W2T, float* __restrict__ bqkv,
    float* __restrict__ lvec)
{
  __shared__ float tile[32][33];
  int b = blockIdx.x, tid = threadIdx.x;
  if (b < 4096) {                        // emb cast
    int idx = b * 256 + tid;
    float4 v = ((const float4*)emb)[idx];
    ushort4 o; o.x = f2bf(v.x); o.y = f2bf(v.y); o.z = f2bf(v.z); o.w = f2bf(v.w);
    ((ushort4*)embB)[idx] = o;
    return;
  }
  int tx = tid & 31, ty = tid >> 5;
  if (b < 7168) {                        // Wq/Wk/Wv -> WqkvT
    int local = b - 4096;
    const float* in = (local < 1024) ? Wq : (local < 2048) ? Wk : Wv;
    uint16_t* o = WqkvT + (size_t)(local >> 10) * 1048576;
    int rem = local & 1023;
    int r0 = (rem >> 5) * 32, c0 = (rem & 31) * 32;
#pragma unroll
    for (int r = 0; r < 32; r += 8)
      tile[ty + r][tx] = in[(size_t)(r0 + ty + r) * 1024 + c0 + tx];
    __syncthreads();
#pragma unroll
    for (int r = 0; r < 32; r += 8)
      o[(size_t)(c0 + ty + r) * 1024 + r0 + tx] = f2bf(tile[tx][ty + r]);
    return;
  }
  if (b < 11264) {                       // W1 -> W1T
    int local = b - 7168;
    int c0 = (local & 127) * 32, r0 = (local >> 7) * 32;
#pragma unroll
    for (int r = 0; r < 32; r += 8)
      tile[ty + r][tx] = W1[(size_t)(r0 + ty + r) * 4096 + c0 + tx];
    __syncthreads();
#pragma unroll
    for (int r = 0; r < 32; r += 8)
      W1T[(size_t)(c0 + ty + r) * 1024 + r0 + tx] = f2bf(tile[tx][ty + r]);
    return;
  }
  if (b < 15360) {                       // W2 -> W2T
    int local = b - 11264;
    int c0 = (local & 31) * 32, r0 = (local >> 5) * 32;
#pragma unroll
    for (int r = 0; r < 32; r += 8)
      tile[ty + r][tx] = W2[(size_t)(r0 + ty + r) * 1024 + c0 + tx];
    __syncthreads();
#pragma unroll
    for (int r = 0; r < 32; r += 8)
      W2T[(size_t)(c0 + ty + r) * 4096 + r0 + tx] = f2bf(tile[tx][ty + r]);
    return;
  }
  if (b < 15372) {                       // pack bq|bk|bv
    int i = (b - 15360) * 256 + tid;
    bqkv[i] = (i < 1024) ? bq[i] : (i < 2048) ? bk[i - 1024] : bv[i - 2048];
    return;
  }
  {                                      // lvec = 0
#pragma unroll
    for (int i = tid; i < 4096; i += 256) lvec[i] = 0.0f;
  }
}

// ---------------- launcher --------------------------------------------------
extern "C" void kernel_launch(void* const* d_in, const int* in_sizes, int n_in,
                              void* d_out, int out_size, void* d_ws, size_t ws_size,
                              hipStream_t stream) {
  const float* emb   = (const float*)d_in[0];
  const float* Wq    = (const float*)d_in[1];
  const float* bq    = (const float*)d_in[2];
  const float* Wk    = (const float*)d_in[3];
  const float* bk    = (const float*)d_in[4];
  const float* Wv    = (const float*)d_in[5];
  const float* bv    = (const float*)d_in[6];
  const float* gamma = (const float*)d_in[7];
  const float* beta  = (const float*)d_in[8];
  const float* W1    = (const float*)d_in[9];
  const float* b1    = (const float*)d_in[10];
  const float* W2    = (const float*)d_in[11];
  const float* b2    = (const float*)d_in[12];

  char* w = (char*)d_ws;
  const size_t MB = 1ull << 20;
  uint16_t* embB  = (uint16_t*)(w + 0 * MB);    // [4096,1024] bf16
  uint16_t* WqkvT = (uint16_t*)(w + 8 * MB);    // [3072,1024]
  uint16_t* W1T   = (uint16_t*)(w + 14 * MB);   // [4096,1024]
  uint16_t* W2T   = (uint16_t*)(w + 22 * MB);   // [1024,4096]
  float*    bqkv  = (float*)(w + 30 * MB);      // [3072]
  float*    lvec  = (float*)(w + 30 * MB + 65536); // [4096]
  uint16_t* QKVb  = (uint16_t*)(w + 31 * MB);   // [4096,3072] (V cols unused)
  uint16_t* Vt    = (uint16_t*)(w + 55 * MB);   // [1024,4096]
  uint16_t* Sb    = (uint16_t*)(w + 63 * MB);   // [4096,4096] bf16 exp(S)
  uint16_t* hB    = (uint16_t*)(w + 63 * MB);   // reuses Sb (dead after O)
  uint16_t* Opart = (uint16_t*)(w + 95 * MB);   // [4][4096,1024] bf16 chunks
  uint16_t* xB    = (uint16_t*)(w + 0 * MB);    // reuses embB
  // total ws requirement: 127 MB

  prep<<<15373, 256, 0, stream>>>(emb, Wq, Wk, Wv, W1, W2, bq, bk, bv,
                                  embB, WqkvT, W1T, W2T, bqkv, lvec);

  // fused QKV: Q,K -> QKVb; V -> Vt via operand-swapped MFMA; bn-owned XCDs
  gemm_qkv<<<768, 256, 0, stream>>>(embB, WqkvT, bqkv, QKVb, Vt);
  const uint16_t* Qb = QKVb;
  const uint16_t* Kb = QKVb + 1024;

  // exp(S): 64x128 causal tiles, XCD-swizzled 2048-slot launch
  gemm_s<<<2048, 256, 0, stream>>>(Qb, Kb, Sb, lvec, 3072, 3072, 4096, 0.03125f);

  // O' = exp(S) @ V: 128x128 triangular K-chunks, XCD-swizzled, long-first
  gemm_o<<<640, 256, 0, stream>>>(Sb, Vt, Opart);

  // reduce O bf16 chunk-partials, /l, + residual, LayerNorm -> xB
  add_layernorm<<<4096, 256, 0, stream>>>(Opart, lvec, emb, gamma, beta, xB);

  // FFN1: counted-vmcnt depth-2 pipeline, quad XCD map
  gemm_ffn1<<<1024, 256, 0, stream>>>(xB, W1T, b1, hB);

  // FFN2: dual-K-group 512-thread blocks (frozen, r23 best)
  gemm_ffn2<<<512, 512, 0, stream>>>(hB, W2T, b2, (float*)d_out);
}